// Round 9
// baseline (84.962 us; speedup 1.0000x reference)
//
#include <hip/hip_runtime.h>

#define BB    256
#define NVERT 10475
#define NKPT  144
#define MVERT 778
#define MKPT  21
#define NBDRY 8192
#define KNB   9
#define ITERS 5
#define NV3   (NVERT * 3)
#define MV3   (MVERT * 3)   // 2334

typedef float f32x4 __attribute__((ext_vector_type(4)));

static __device__ __forceinline__ float bfu(unsigned hi16) {
    return __uint_as_float(hi16);
}
// f32 -> bf16 bits, round-to-nearest-even
static __device__ __forceinline__ unsigned f2bf(float f) {
    unsigned u = __float_as_uint(f);
    u += 0x7FFFu + ((u >> 16) & 1u);
    return u >> 16;
}
static __device__ __forceinline__ uint2 packv(float x, float y, float z) {
    return make_uint2(f2bf(x) | (f2bf(y) << 16), f2bf(z));
}
// scalar fallback pack (head/tail): dword position p -> vertex p/3, comp p%3
static __device__ __forceinline__ void pack_one(unsigned short* msh16, unsigned p, float val) {
    unsigned v = p / 3u;
    unsigned c = p - v * 3u;
    msh16[v * 4u + c] = (unsigned short)f2bf(val);
}

// dense f32x4 copy global -> LDS staging
static __device__ __forceinline__ void stage_load(const float* __restrict__ g,
                                                  float* sh, int n, int t, int nt) {
    unsigned lead = (4u - ((unsigned)(((size_t)g) >> 2) & 3u)) & 3u;
    unsigned nb4 = ((unsigned)n - lead) >> 2;
    if (t == 0) for (unsigned e = 0; e < lead; ++e) sh[e] = g[e];
    if (t == 1) for (unsigned e = lead + 4u * nb4; e < (unsigned)n; ++e) sh[e] = g[e];
    const f32x4* g4 = (const f32x4*)(g + lead);
    for (unsigned i4 = (unsigned)t; i4 < nb4; i4 += (unsigned)nt) {
        f32x4 q = g4[i4];
        unsigned p = lead + 4u * i4;
        sh[p] = q.x; sh[p + 1] = q.y; sh[p + 2] = q.z; sh[p + 3] = q.w;
    }
}

// ---------------------------------------------------------------------------
// Per (batch, hand) rigid alignment. f32; Jacobi fully unrolled (registers).
// ---------------------------------------------------------------------------
static __device__ void compute_align(
    int b, int h,
    const float* __restrict__ skpt, const float* __restrict__ rkpt,
    const float* __restrict__ lkpt, const float* __restrict__ rpose,
    const float* __restrict__ lpose, const int* __restrict__ perm,
    const int* __restrict__ ralign, const int* __restrict__ lalign,
    float* o)
{
    const float* pose = (h ? lpose : rpose) + b * 3;
    const float* kpt  = (h ? lkpt : rkpt) + (size_t)b * MKPT * 3;
    const int* alidx  = h ? lalign : ralign;

    float ax = pose[0], ay = pose[1], az = pose[2];
    float ang = sqrtf(ax*ax + ay*ay + az*az);
    float ia = 1.0f / (ang + 1e-8f);
    float x = ax*ia, y = ay*ia, z = az*ia;
    float c = cosf(ang), s = sinf(ang), Cc = 1.0f - c;
    float A00 = c + x*x*Cc,   A01 = x*y*Cc - z*s, A02 = x*z*Cc + y*s;
    float A10 = y*x*Cc + z*s, A11 = c + y*y*Cc,   A12 = y*z*Cc - x*s;
    float A20 = z*x*Cc - y*s, A21 = z*y*Cc + x*s, A22 = c + z*z*Cc;

    float sX0=0,sX1=0,sX2=0, sY0=0,sY1=0,sY2=0;
    float S00=0,S01=0,S02=0,S10=0,S11=0,S12=0,S20=0,S21=0,S22=0;
    for (int n = 0; n < MKPT; ++n) {
        int pi = perm[n];
        float p0 = kpt[pi*3+0], p1 = kpt[pi*3+1], p2 = kpt[pi*3+2];
        float X0 = A00*p0 + A10*p1 + A20*p2;
        float X1 = A01*p0 + A11*p1 + A21*p2;
        float X2 = A02*p0 + A12*p1 + A22*p2;
        int qi = alidx[n];
        const float* yp = skpt + ((size_t)b * NKPT + qi) * 3;
        float Y0 = yp[0], Y1 = yp[1], Y2 = yp[2];
        sX0 += X0; sX1 += X1; sX2 += X2;
        sY0 += Y0; sY1 += Y1; sY2 += Y2;
        S00 += X0*Y0; S01 += X0*Y1; S02 += X0*Y2;
        S10 += X1*Y0; S11 += X1*Y1; S12 += X1*Y2;
        S20 += X2*Y0; S21 += X2*Y1; S22 += X2*Y2;
    }
    const float invN = 1.0f / (float)MKPT;
    float C00 = S00 - sX0*sY0*invN, C01 = S01 - sX0*sY1*invN, C02 = S02 - sX0*sY2*invN;
    float C10 = S10 - sX1*sY0*invN, C11 = S11 - sX1*sY1*invN, C12 = S12 - sX1*sY2*invN;
    float C20 = S20 - sX2*sY0*invN, C21 = S21 - sX2*sY1*invN, C22 = S22 - sX2*sY2*invN;

    float N[4][4];
    N[0][0] = C00 + C11 + C22;
    N[0][1] = C21 - C12; N[0][2] = C02 - C20; N[0][3] = C10 - C01;
    N[1][1] = C00 - C11 - C22; N[1][2] = C01 + C10; N[1][3] = C02 + C20;
    N[2][2] = -C00 + C11 - C22; N[2][3] = C12 + C21;
    N[3][3] = -C00 - C11 + C22;
    N[1][0] = N[0][1]; N[2][0] = N[0][2]; N[3][0] = N[0][3];
    N[2][1] = N[1][2]; N[3][1] = N[1][3]; N[3][2] = N[2][3];

    float V[4][4] = {{1,0,0,0},{0,1,0,0},{0,0,1,0},{0,0,0,1}};
    for (int sweep = 0; sweep < 10; ++sweep) {
        float off = N[0][1]*N[0][1] + N[0][2]*N[0][2] + N[0][3]*N[0][3]
                  + N[1][2]*N[1][2] + N[1][3]*N[1][3] + N[2][3]*N[2][3];
        if (off < 1e-12f) break;
        #pragma unroll
        for (int p = 0; p < 3; ++p) {
            #pragma unroll
            for (int q = p + 1; q < 4; ++q) {
                float apq = N[p][q];
                if (fabsf(apq) > 1e-30f) {
                    float theta = (N[q][q] - N[p][p]) / (2.0f * apq);
                    float tt = copysignf(1.0f, theta) / (fabsf(theta) + sqrtf(theta*theta + 1.0f));
                    float cj = rsqrtf(tt*tt + 1.0f);
                    float sj = tt * cj;
                    #pragma unroll
                    for (int k = 0; k < 4; ++k) {
                        float akp = N[k][p], akq = N[k][q];
                        N[k][p] = cj*akp - sj*akq;
                        N[k][q] = sj*akp + cj*akq;
                    }
                    #pragma unroll
                    for (int k = 0; k < 4; ++k) {
                        float apk = N[p][k], aqk = N[q][k];
                        N[p][k] = cj*apk - sj*aqk;
                        N[q][k] = sj*apk + cj*aqk;
                    }
                    #pragma unroll
                    for (int k = 0; k < 4; ++k) {
                        float vkp = V[k][p], vkq = V[k][q];
                        V[k][p] = cj*vkp - sj*vkq;
                        V[k][q] = sj*vkp + cj*vkq;
                    }
                }
            }
        }
    }
    int m = 0;
    float lmax = N[0][0];
    if (N[1][1] > lmax) { lmax = N[1][1]; m = 1; }
    if (N[2][2] > lmax) { lmax = N[2][2]; m = 2; }
    if (N[3][3] > lmax) { lmax = N[3][3]; m = 3; }
    float w = V[0][m], qx = V[1][m], qy = V[2][m], qz = V[3][m];

    float R00 = 1.0f - 2.0f*(qy*qy + qz*qz), R01 = 2.0f*(qx*qy - w*qz), R02 = 2.0f*(qx*qz + w*qy);
    float R10 = 2.0f*(qx*qy + w*qz), R11 = 1.0f - 2.0f*(qx*qx + qz*qz), R12 = 2.0f*(qy*qz - w*qx);
    float R20 = 2.0f*(qx*qz - w*qy), R21 = 2.0f*(qy*qz + w*qx), R22 = 1.0f - 2.0f*(qx*qx + qy*qy);

    float mX0 = sX0*invN, mX1 = sX1*invN, mX2 = sX2*invN;
    float mY0 = sY0*invN, mY1 = sY1*invN, mY2 = sY2*invN;

    o[0]  = A00*R00 + A01*R10 + A02*R20;
    o[1]  = A00*R01 + A01*R11 + A02*R21;
    o[2]  = A00*R02 + A01*R12 + A02*R22;
    o[3]  = A10*R00 + A11*R10 + A12*R20;
    o[4]  = A10*R01 + A11*R11 + A12*R21;
    o[5]  = A10*R02 + A11*R12 + A12*R22;
    o[6]  = A20*R00 + A21*R10 + A22*R20;
    o[7]  = A20*R01 + A21*R11 + A22*R21;
    o[8]  = A20*R02 + A21*R12 + A22*R22;
    o[9]  = mY0 - (mX0*R00 + mX1*R10 + mX2*R20);
    o[10] = mY1 - (mX0*R01 + mX1*R11 + mX2*R21);
    o[11] = mY2 - (mX0*R02 + mX1*R12 + mX2*R22);
}

// ---------------------------------------------------------------------------
// Pack kernel (64 blocks x 128 thr): each block builds the boundary-flag table
// in its own LDS, then packs 128 records: dynamic (in-boundary) neighbor idxs
// in low slots, static in high slots, dummies between. Counts in spare bits:
//   w0 = s0|s1<<14|dcnt<<28   w1 = s2|s3<<14|vcnt<<28
//   w2 = s4|s5<<14            w3 = s6|s7<<14
//   w4 = s8|bi<<14|scnt<<28
// ---------------------------------------------------------------------------
__global__ __launch_bounds__(128) void pack_kernel(
    const int* __restrict__ bidx, const int* __restrict__ vnbr,
    unsigned* __restrict__ tab)
{
    __shared__ unsigned char flag[NVERT];
    const int tid = threadIdx.x;
    for (int i = tid; i < NVERT; i += 128) flag[i] = 0;
    __syncthreads();
    for (int j = tid; j < NBDRY; j += 128) flag[bidx[j]] = 1;
    __syncthreads();
    int j = blockIdx.x * 128 + tid;
    int bi = bidx[j];
    const int* row = vnbr + (size_t)bi * KNB;
    unsigned slot[9];
    #pragma unroll
    for (int e = 0; e < 9; ++e) slot[e] = (unsigned)NVERT;
    int dc = 0, sc = 0;
    #pragma unroll
    for (int e = 0; e < 9; ++e) {
        int v = row[e];
        if (v >= 0) {
            if (flag[v]) slot[dc++] = (unsigned)v;
            else         slot[8 - (sc++)] = (unsigned)v;
        }
    }
    unsigned vcnt = (unsigned)(dc + sc);
    if (vcnt == 0u) vcnt = 1u;
    tab[0 * NBDRY + j] = slot[0] | (slot[1] << 14) | ((unsigned)dc << 28);
    tab[1 * NBDRY + j] = slot[2] | (slot[3] << 14) | (vcnt << 28);
    tab[2 * NBDRY + j] = slot[4] | (slot[5] << 14);
    tab[3 * NBDRY + j] = slot[6] | (slot[7] << 14);
    tab[4 * NBDRY + j] = slot[8] | ((unsigned)bi << 14) | ((unsigned)sc << 28);
}

// ---------------------------------------------------------------------------
// Main fused kernel: one workgroup (1024 thr) per batch.
// LDS pool: mesh (83.8 KB) + overlay region (64 KB) shared by hstage (phase B)
// then per-record static sums (loop). Per-thread regs: w[40]+up[16]=56 (no spill).
// ---------------------------------------------------------------------------
__global__ __launch_bounds__(1024, 1) void fused_kernel(
    const float* __restrict__ svert,  // [B, NVERT, 3]
    const float* __restrict__ skpt,   // [B, NKPT, 3]
    const float* __restrict__ rv,     // [B, MVERT, 3]
    const float* __restrict__ rkpt,   // [B, MKPT, 3]
    const float* __restrict__ rpose,  // [B, 3]
    const float* __restrict__ lv,
    const float* __restrict__ lkpt,
    const float* __restrict__ lpose,
    const int*   __restrict__ perm,
    const int*   __restrict__ ralign,
    const int*   __restrict__ lalign,
    const int*   __restrict__ ridx,   // [MVERT]
    const int*   __restrict__ lidx,
    const unsigned* __restrict__ tab, // [5, NBDRY]
    float*       __restrict__ out)    // [B, NVERT, 3]
{
    __shared__ __align__(16) unsigned long long pool64[(83808 + 65536) / 8];
    __shared__ float affsh[24];
    unsigned short* msh16 = (unsigned short*)pool64;
    uint2* meshw = (uint2*)pool64;
    float* hstage = (float*)((char*)pool64 + 83808);   // 18.7 KB, phase A/B only
    uint2* ssum   = (uint2*)((char*)pool64 + 83808);   // 64 KB, after phase B
    const int b = blockIdx.x;
    const int tid = threadIdx.x;

    // ---- phase A: align (lanes 0,1) || staging (tid>=64), vertex-aligned ----
    if (tid < 2) {
        compute_align(b, tid, skpt, rkpt, lkpt, rpose, lpose,
                      perm, ralign, lalign, affsh + tid * 12);
    } else if (tid == 2) {
        meshw[NVERT] = make_uint2(0u, 0u);  // dummy slot
    } else if (tid >= 64) {
        const int t = tid - 64;
        const float* g = svert + (size_t)b * NV3;
        unsigned lead = (4u - ((unsigned)(((size_t)g) >> 2) & 3u)) & 3u;
        unsigned r0 = lead % 3u;
        unsigned qb = (lead - r0) / 3u;
        unsigned ng = ((unsigned)NV3 - lead) / 12u;
        const f32x4* s4 = (const f32x4*)(g + lead);
        if (t == 0) for (unsigned d = 0; d < lead; ++d) pack_one(msh16, d, g[d]);
        if (t == 1) for (unsigned d = lead + 12u * ng; d < (unsigned)NV3; ++d) pack_one(msh16, d, g[d]);
        if (r0 == 0u) {
            for (unsigned gi = (unsigned)t; gi < ng; gi += 960u) {
                f32x4 a = s4[3*gi], c = s4[3*gi+1], e = s4[3*gi+2];
                unsigned q = qb + 4u * gi;
                meshw[q]     = packv(a.x, a.y, a.z);
                meshw[q + 1] = packv(a.w, c.x, c.y);
                meshw[q + 2] = packv(c.z, c.w, e.x);
                meshw[q + 3] = packv(e.y, e.z, e.w);
            }
        } else if (r0 == 1u) {
            for (unsigned gi = (unsigned)t; gi < ng; gi += 960u) {
                f32x4 a = s4[3*gi], c = s4[3*gi+1], e = s4[3*gi+2];
                unsigned q = qb + 4u * gi;
                msh16[4u*q + 1] = (unsigned short)f2bf(a.x);
                msh16[4u*q + 2] = (unsigned short)f2bf(a.y);
                meshw[q + 1] = packv(a.z, a.w, c.x);
                meshw[q + 2] = packv(c.y, c.z, c.w);
                meshw[q + 3] = packv(e.x, e.y, e.z);
                msh16[4u*(q + 4)] = (unsigned short)f2bf(e.w);
            }
        } else {
            for (unsigned gi = (unsigned)t; gi < ng; gi += 960u) {
                f32x4 a = s4[3*gi], c = s4[3*gi+1], e = s4[3*gi+2];
                unsigned q = qb + 4u * gi;
                msh16[4u*q + 2] = (unsigned short)f2bf(a.x);
                meshw[q + 1] = packv(a.y, a.z, a.w);
                meshw[q + 2] = packv(c.x, c.y, c.z);
                meshw[q + 3] = packv(c.w, e.x, e.y);
                ((unsigned*)msh16)[2u*(q + 4)] = f2bf(e.z) | (f2bf(e.w) << 16);
            }
        }
        stage_load(rv + (size_t)b * MV3, hstage,       MV3, t, 960);
        stage_load(lv + (size_t)b * MV3, hstage + MV3, MV3, t, 960);
    }

    // coalesced table reads (all threads, 8 records each)
    unsigned w0[8], w1[8], w2[8], w3[8], w4[8];
    #pragma unroll
    for (int k = 0; k < 8; ++k) {
        int j = k * 1024 + tid;
        w0[k] = tab[j];
        w1[k] = tab[NBDRY + j];
        w2[k] = tab[2 * NBDRY + j];
        w3[k] = tab[3 * NBDRY + j];
        w4[k] = tab[4 * NBDRY + j];
    }
    __syncthreads();   // mesh+hands staged, affines ready

    // ---- phase B: transform + scatter hand verts ----
    for (int i = tid; i < 2 * MVERT; i += 1024) {
        int h = (i >= MVERT) ? 1 : 0;
        int nn = i - h * MVERT;
        const int* hidx = h ? lidx : ridx;
        const float* M = affsh + h * 12;
        const float* p = hstage + h * MV3 + nn * 3;
        float p0 = p[0], p1 = p[1], p2 = p[2];
        float o0 = p0 * M[0] + p1 * M[3] + p2 * M[6] + M[9];
        float o1 = p0 * M[1] + p1 * M[4] + p2 * M[7] + M[10];
        float o2 = p0 * M[2] + p1 * M[5] + p2 * M[8] + M[11];
        meshw[hidx[nn]] = packv(o0, o1, o2);
    }
    __syncthreads();   // scatter done; hstage dead -> ssum overlay live

#define ADD3(IDX, X, Y, Z) { uint2 m_ = meshw[(IDX)]; \
        X += bfu(m_.x << 16); Y += bfu(m_.x & 0xFFFF0000u); Z += bfu(m_.y << 16); }

    // ---- static sums (once) + self values -> registers ----
    uint2 up[8];
    #pragma unroll
    for (int k = 0; k < 8; ++k) {
        unsigned a0 = w0[k], a1 = w1[k], a2 = w2[k], a3 = w3[k], a4 = w4[k];
        up[k] = meshw[(a4 >> 14) & 0x3FFFu];
        int sc = (int)(a4 >> 28);
        float tx = 0.f, ty = 0.f, tz = 0.f;
        if (sc > 0) ADD3(a4 & 0x3FFFu, tx, ty, tz)            // slot 8
        if (sc > 1) ADD3((a3 >> 14) & 0x3FFFu, tx, ty, tz)    // slot 7
        if (sc > 2) ADD3(a3 & 0x3FFFu, tx, ty, tz)
        if (sc > 3) ADD3((a2 >> 14) & 0x3FFFu, tx, ty, tz)
        if (sc > 4) ADD3(a2 & 0x3FFFu, tx, ty, tz)
        if (sc > 5) ADD3((a1 >> 14) & 0x3FFFu, tx, ty, tz)
        if (sc > 6) ADD3(a1 & 0x3FFFu, tx, ty, tz)
        if (sc > 7) ADD3((a0 >> 14) & 0x3FFFu, tx, ty, tz)
        if (sc > 8) ADD3(a0 & 0x3FFFu, tx, ty, tz)
        ssum[k * 1024 + tid] = packv(tx, ty, tz);
    }

    // ---- 5 Jacobi smoothing iterations (dynamic gathers only) ----
    for (int itr = 0; itr < ITERS; ++itr) {
        #pragma unroll
        for (int k = 0; k < 8; ++k) {
            unsigned a0 = w0[k], a1 = w1[k], a2 = w2[k], a3 = w3[k], a4 = w4[k];
            int dc = (int)(a0 >> 28);
            uint2 sv = ssum[k * 1024 + tid];
            float sx = bfu(sv.x << 16), sy = bfu(sv.x & 0xFFFF0000u), sz = bfu(sv.y << 16);
            if (dc > 0) ADD3(a0 & 0x3FFFu, sx, sy, sz)
            if (dc > 1) ADD3((a0 >> 14) & 0x3FFFu, sx, sy, sz)
            if (dc > 2) ADD3(a1 & 0x3FFFu, sx, sy, sz)
            if (dc > 3) ADD3((a1 >> 14) & 0x3FFFu, sx, sy, sz)
            if (dc > 4) ADD3(a2 & 0x3FFFu, sx, sy, sz)
            if (dc > 5) ADD3((a2 >> 14) & 0x3FFFu, sx, sy, sz)
            if (dc > 6) ADD3(a3 & 0x3FFFu, sx, sy, sz)
            if (dc > 7) ADD3((a3 >> 14) & 0x3FFFu, sx, sy, sz)
            if (dc > 8) ADD3(a4 & 0x3FFFu, sx, sy, sz)
            float hinv = 0.5f * __builtin_amdgcn_rcpf((float)(a1 >> 28));
            float ux = 0.5f * bfu(up[k].x << 16)         + hinv * sx;
            float uy = 0.5f * bfu(up[k].x & 0xFFFF0000u) + hinv * sy;
            float uz = 0.5f * bfu(up[k].y << 16)         + hinv * sz;
            up[k] = packv(ux, uy, uz);
        }
        __syncthreads();
        #pragma unroll
        for (int k = 0; k < 8; ++k) {
            meshw[(w4[k] >> 14) & 0x3FFFu] = up[k];
        }
        __syncthreads();
    }
#undef ADD3

    // ---- writeback: vertex-aligned 12-dword groups, wave-uniform r0 branch ----
    float* dst = out + (size_t)b * NV3;
    const unsigned lead = (4u - ((unsigned)(((size_t)dst) >> 2) & 3u)) & 3u;
    const unsigned r0 = lead % 3u;
    const unsigned qb = (lead - r0) / 3u;
    const unsigned ng = ((unsigned)NV3 - lead) / 12u;
    f32x4* d4 = (f32x4*)(dst + lead);
#define COMP(i, val) { unsigned v_ = (i) / 3u; unsigned c_ = (i) - v_ * 3u; \
        uint2 m_ = meshw[v_]; \
        val = (c_ == 0u) ? bfu(m_.x << 16) : (c_ == 1u) ? bfu(m_.x & 0xFFFF0000u) : bfu(m_.y << 16); }
#define MX(m) bfu((m).x << 16)
#define MY(m) bfu((m).x & 0xFFFF0000u)
#define MZ(m) bfu((m).y << 16)
    if (tid == 0) for (unsigned d = 0; d < lead; ++d) { float v; COMP(d, v); dst[d] = v; }
    if (tid == 1) for (unsigned d = lead + 12u * ng; d < (unsigned)NV3; ++d) { float v; COMP(d, v); dst[d] = v; }
    if (r0 == 0u) {
        for (unsigned gi = (unsigned)tid; gi < ng; gi += 1024u) {
            unsigned q = qb + 4u * gi;
            uint2 m0 = meshw[q], m1 = meshw[q+1], m2 = meshw[q+2], m3 = meshw[q+3];
            d4[3*gi]   = (f32x4){MX(m0), MY(m0), MZ(m0), MX(m1)};
            d4[3*gi+1] = (f32x4){MY(m1), MZ(m1), MX(m2), MY(m2)};
            d4[3*gi+2] = (f32x4){MZ(m2), MX(m3), MY(m3), MZ(m3)};
        }
    } else if (r0 == 1u) {
        for (unsigned gi = (unsigned)tid; gi < ng; gi += 1024u) {
            unsigned q = qb + 4u * gi;
            uint2 m0 = meshw[q], m1 = meshw[q+1], m2 = meshw[q+2], m3 = meshw[q+3], m4 = meshw[q+4];
            d4[3*gi]   = (f32x4){MY(m0), MZ(m0), MX(m1), MY(m1)};
            d4[3*gi+1] = (f32x4){MZ(m1), MX(m2), MY(m2), MZ(m2)};
            d4[3*gi+2] = (f32x4){MX(m3), MY(m3), MZ(m3), MX(m4)};
        }
    } else {
        for (unsigned gi = (unsigned)tid; gi < ng; gi += 1024u) {
            unsigned q = qb + 4u * gi;
            uint2 m0 = meshw[q], m1 = meshw[q+1], m2 = meshw[q+2], m3 = meshw[q+3], m4 = meshw[q+4];
            d4[3*gi]   = (f32x4){MZ(m0), MX(m1), MY(m1), MZ(m1)};
            d4[3*gi+1] = (f32x4){MX(m2), MY(m2), MZ(m2), MX(m3)};
            d4[3*gi+2] = (f32x4){MY(m3), MZ(m3), MX(m4), MY(m4)};
        }
    }
#undef COMP
#undef MX
#undef MY
#undef MZ
}

extern "C" void kernel_launch(void* const* d_in, const int* in_sizes, int n_in,
                              void* d_out, int out_size, void* d_ws, size_t ws_size,
                              hipStream_t stream) {
    const float* svert  = (const float*)d_in[0];
    const float* skpt   = (const float*)d_in[1];
    const float* rv     = (const float*)d_in[2];
    const float* rk     = (const float*)d_in[3];
    const float* rpose  = (const float*)d_in[4];
    const float* lv     = (const float*)d_in[5];
    const float* lk     = (const float*)d_in[6];
    const float* lpose  = (const float*)d_in[7];
    const int*   perm   = (const int*)d_in[8];
    const int*   ralign = (const int*)d_in[9];
    const int*   lalign = (const int*)d_in[10];
    const int*   ridx   = (const int*)d_in[11];
    const int*   lidx   = (const int*)d_in[12];
    const int*   bidx   = (const int*)d_in[15];
    const int*   vnbr   = (const int*)d_in[16];
    float* out = (float*)d_out;

    unsigned* tab = (unsigned*)d_ws;   // 5*8192 u32 = 160 KB

    pack_kernel<<<64, 128, 0, stream>>>(bidx, vnbr, tab);
    fused_kernel<<<BB, 1024, 0, stream>>>(svert, skpt, rv, rk, rpose,
                                          lv, lk, lpose, perm, ralign, lalign,
                                          ridx, lidx, tab, out);
}

// Round 10
// 62.676 us; speedup vs baseline: 1.3556x; 1.3556x over previous
//
#include <hip/hip_runtime.h>

#define BB    256
#define NVERT 10475
#define NKPT  144
#define MVERT 778
#define MKPT  21
#define NBDRY 8192
#define KNB   9
#define ITERS 5
#define NV3   (NVERT * 3)
#define MV3   (MVERT * 3)   // 2334

typedef float f32x4 __attribute__((ext_vector_type(4)));

static __device__ __forceinline__ float bfu(unsigned hi16) {
    return __uint_as_float(hi16);
}
// f32 -> bf16 bits, round-to-nearest-even
static __device__ __forceinline__ unsigned f2bf(float f) {
    unsigned u = __float_as_uint(f);
    u += 0x7FFFu + ((u >> 16) & 1u);
    return u >> 16;
}
// pack one float (global dword position p within the batch slice) into the
// bf16 mesh: vertex = p/3, component = p%3, stored as ushort at v*4+c.
static __device__ __forceinline__ void pack_one(unsigned short* msh16, unsigned p, float val) {
    unsigned v = p / 3u;
    unsigned c = p - v * 3u;
    msh16[v * 4u + c] = (unsigned short)f2bf(val);
}

// dense f32x4 copy global -> LDS staging
static __device__ __forceinline__ void stage_load(const float* __restrict__ g,
                                                  float* sh, int n, int t, int nt) {
    unsigned lead = (4u - ((unsigned)(((size_t)g) >> 2) & 3u)) & 3u;
    unsigned nb4 = ((unsigned)n - lead) >> 2;
    if (t == 0) for (unsigned e = 0; e < lead; ++e) sh[e] = g[e];
    if (t == 1) for (unsigned e = lead + 4u * nb4; e < (unsigned)n; ++e) sh[e] = g[e];
    const f32x4* g4 = (const f32x4*)(g + lead);
    for (unsigned i4 = (unsigned)t; i4 < nb4; i4 += (unsigned)nt) {
        f32x4 q = g4[i4];
        unsigned p = lead + 4u * i4;
        sh[p] = q.x; sh[p + 1] = q.y; sh[p + 2] = q.z; sh[p + 3] = q.w;
    }
}

// ---------------------------------------------------------------------------
// Per (batch, hand) rigid alignment. f32; Jacobi fully unrolled (registers).
// ---------------------------------------------------------------------------
static __device__ void compute_align(
    int b, int h,
    const float* __restrict__ skpt, const float* __restrict__ rkpt,
    const float* __restrict__ lkpt, const float* __restrict__ rpose,
    const float* __restrict__ lpose, const int* __restrict__ perm,
    const int* __restrict__ ralign, const int* __restrict__ lalign,
    float* o)
{
    const float* pose = (h ? lpose : rpose) + b * 3;
    const float* kpt  = (h ? lkpt : rkpt) + (size_t)b * MKPT * 3;
    const int* alidx  = h ? lalign : ralign;

    float ax = pose[0], ay = pose[1], az = pose[2];
    float ang = sqrtf(ax*ax + ay*ay + az*az);
    float ia = 1.0f / (ang + 1e-8f);
    float x = ax*ia, y = ay*ia, z = az*ia;
    float c = cosf(ang), s = sinf(ang), Cc = 1.0f - c;
    float A00 = c + x*x*Cc,   A01 = x*y*Cc - z*s, A02 = x*z*Cc + y*s;
    float A10 = y*x*Cc + z*s, A11 = c + y*y*Cc,   A12 = y*z*Cc - x*s;
    float A20 = z*x*Cc - y*s, A21 = z*y*Cc + x*s, A22 = c + z*z*Cc;

    float sX0=0,sX1=0,sX2=0, sY0=0,sY1=0,sY2=0;
    float S00=0,S01=0,S02=0,S10=0,S11=0,S12=0,S20=0,S21=0,S22=0;
    for (int n = 0; n < MKPT; ++n) {
        int pi = perm[n];
        float p0 = kpt[pi*3+0], p1 = kpt[pi*3+1], p2 = kpt[pi*3+2];
        float X0 = A00*p0 + A10*p1 + A20*p2;
        float X1 = A01*p0 + A11*p1 + A21*p2;
        float X2 = A02*p0 + A12*p1 + A22*p2;
        int qi = alidx[n];
        const float* yp = skpt + ((size_t)b * NKPT + qi) * 3;
        float Y0 = yp[0], Y1 = yp[1], Y2 = yp[2];
        sX0 += X0; sX1 += X1; sX2 += X2;
        sY0 += Y0; sY1 += Y1; sY2 += Y2;
        S00 += X0*Y0; S01 += X0*Y1; S02 += X0*Y2;
        S10 += X1*Y0; S11 += X1*Y1; S12 += X1*Y2;
        S20 += X2*Y0; S21 += X2*Y1; S22 += X2*Y2;
    }
    const float invN = 1.0f / (float)MKPT;
    float C00 = S00 - sX0*sY0*invN, C01 = S01 - sX0*sY1*invN, C02 = S02 - sX0*sY2*invN;
    float C10 = S10 - sX1*sY0*invN, C11 = S11 - sX1*sY1*invN, C12 = S12 - sX1*sY2*invN;
    float C20 = S20 - sX2*sY0*invN, C21 = S21 - sX2*sY1*invN, C22 = S22 - sX2*sY2*invN;

    float N[4][4];
    N[0][0] = C00 + C11 + C22;
    N[0][1] = C21 - C12; N[0][2] = C02 - C20; N[0][3] = C10 - C01;
    N[1][1] = C00 - C11 - C22; N[1][2] = C01 + C10; N[1][3] = C02 + C20;
    N[2][2] = -C00 + C11 - C22; N[2][3] = C12 + C21;
    N[3][3] = -C00 - C11 + C22;
    N[1][0] = N[0][1]; N[2][0] = N[0][2]; N[3][0] = N[0][3];
    N[2][1] = N[1][2]; N[3][1] = N[1][3]; N[3][2] = N[2][3];

    float V[4][4] = {{1,0,0,0},{0,1,0,0},{0,0,1,0},{0,0,0,1}};
    for (int sweep = 0; sweep < 10; ++sweep) {
        float off = N[0][1]*N[0][1] + N[0][2]*N[0][2] + N[0][3]*N[0][3]
                  + N[1][2]*N[1][2] + N[1][3]*N[1][3] + N[2][3]*N[2][3];
        if (off < 1e-12f) break;
        #pragma unroll
        for (int p = 0; p < 3; ++p) {
            #pragma unroll
            for (int q = p + 1; q < 4; ++q) {
                float apq = N[p][q];
                if (fabsf(apq) > 1e-30f) {
                    float theta = (N[q][q] - N[p][p]) / (2.0f * apq);
                    float tt = copysignf(1.0f, theta) / (fabsf(theta) + sqrtf(theta*theta + 1.0f));
                    float cj = rsqrtf(tt*tt + 1.0f);
                    float sj = tt * cj;
                    #pragma unroll
                    for (int k = 0; k < 4; ++k) {
                        float akp = N[k][p], akq = N[k][q];
                        N[k][p] = cj*akp - sj*akq;
                        N[k][q] = sj*akp + cj*akq;
                    }
                    #pragma unroll
                    for (int k = 0; k < 4; ++k) {
                        float apk = N[p][k], aqk = N[q][k];
                        N[p][k] = cj*apk - sj*aqk;
                        N[q][k] = sj*apk + cj*aqk;
                    }
                    #pragma unroll
                    for (int k = 0; k < 4; ++k) {
                        float vkp = V[k][p], vkq = V[k][q];
                        V[k][p] = cj*vkp - sj*vkq;
                        V[k][q] = sj*vkp + cj*vkq;
                    }
                }
            }
        }
    }
    int m = 0;
    float lmax = N[0][0];
    if (N[1][1] > lmax) { lmax = N[1][1]; m = 1; }
    if (N[2][2] > lmax) { lmax = N[2][2]; m = 2; }
    if (N[3][3] > lmax) { lmax = N[3][3]; m = 3; }
    float w = V[0][m], qx = V[1][m], qy = V[2][m], qz = V[3][m];

    float R00 = 1.0f - 2.0f*(qy*qy + qz*qz), R01 = 2.0f*(qx*qy - w*qz), R02 = 2.0f*(qx*qz + w*qy);
    float R10 = 2.0f*(qx*qy + w*qz), R11 = 1.0f - 2.0f*(qx*qx + qz*qz), R12 = 2.0f*(qy*qz - w*qx);
    float R20 = 2.0f*(qx*qz - w*qy), R21 = 2.0f*(qy*qz + w*qx), R22 = 1.0f - 2.0f*(qx*qx + qy*qy);

    float mX0 = sX0*invN, mX1 = sX1*invN, mX2 = sX2*invN;
    float mY0 = sY0*invN, mY1 = sY1*invN, mY2 = sY2*invN;

    o[0]  = A00*R00 + A01*R10 + A02*R20;
    o[1]  = A00*R01 + A01*R11 + A02*R21;
    o[2]  = A00*R02 + A01*R12 + A02*R22;
    o[3]  = A10*R00 + A11*R10 + A12*R20;
    o[4]  = A10*R01 + A11*R11 + A12*R21;
    o[5]  = A10*R02 + A11*R12 + A12*R22;
    o[6]  = A20*R00 + A21*R10 + A22*R20;
    o[7]  = A20*R01 + A21*R11 + A22*R21;
    o[8]  = A20*R02 + A21*R12 + A22*R22;
    o[9]  = mY0 - (mX0*R00 + mX1*R10 + mX2*R20);
    o[10] = mY1 - (mX0*R01 + mX1*R11 + mX2*R21);
    o[11] = mY2 - (mX0*R02 + mX1*R12 + mX2*R22);
}

// ---------------------------------------------------------------------------
// Pack-only kernel (64 blocks x 128 thr): the address-divergent vnbr-row
// gathers paid once, spread over 64 CUs. Simple slot order (round-8 layout):
//   w0..w3 = n0..n7 pairs (14b, invalid -> NVERT dummy)
//   w4     = n8 | bi<<14 | cnt<<28
// ---------------------------------------------------------------------------
__global__ __launch_bounds__(128) void pack_kernel(
    const int* __restrict__ bidx, const int* __restrict__ vnbr,
    unsigned* __restrict__ tab)
{
    int j = blockIdx.x * 128 + threadIdx.x; // 0..8191
    int bi = bidx[j];
    const int* row = vnbr + (size_t)bi * KNB;
    unsigned n[9]; unsigned cnt = 0;
    #pragma unroll
    for (int e = 0; e < 9; ++e) {
        int vv = row[e];
        if (vv >= 0) { n[e] = (unsigned)vv; ++cnt; }
        else         { n[e] = (unsigned)NVERT; }
    }
    if (cnt == 0) cnt = 1;
    tab[0 * NBDRY + j] = n[0] | (n[1] << 14);
    tab[1 * NBDRY + j] = n[2] | (n[3] << 14);
    tab[2 * NBDRY + j] = n[4] | (n[5] << 14);
    tab[3 * NBDRY + j] = n[6] | (n[7] << 14);
    tab[4 * NBDRY + j] = n[8] | ((unsigned)bi << 14) | (cnt << 28);
}

// ---------------------------------------------------------------------------
// Main fused kernel (round-8 structure + inline align): one WG (1024) / batch.
// Per-thread state <= ~56 VGPRs (w0..w4[8]=40 + up[8]=16): spill-free.
// Branchless 9-gather loop (wave-level LDS instruction count is the cost).
// ---------------------------------------------------------------------------
__global__ __launch_bounds__(1024, 1) void fused_kernel(
    const float* __restrict__ svert,  // [B, NVERT, 3]
    const float* __restrict__ skpt,   // [B, NKPT, 3]
    const float* __restrict__ rv,     // [B, MVERT, 3]
    const float* __restrict__ rkpt,   // [B, MKPT, 3]
    const float* __restrict__ rpose,  // [B, 3]
    const float* __restrict__ lv,
    const float* __restrict__ lkpt,
    const float* __restrict__ lpose,
    const int*   __restrict__ perm,
    const int*   __restrict__ ralign,
    const int*   __restrict__ lalign,
    const int*   __restrict__ ridx,   // [MVERT]
    const int*   __restrict__ lidx,
    const unsigned* __restrict__ tab, // [5, NBDRY]
    float*       __restrict__ out)    // [B, NVERT, 3]
{
    __shared__ __align__(16) unsigned short msh16[(NVERT + 1) * 4];  // 83.8 KB
    __shared__ __align__(16) float hstage[2 * MV3];                  // 18.7 KB
    __shared__ float affsh[24];
    const int b = blockIdx.x;
    const int tid = threadIdx.x;

    // ---- phase A: align (lanes 0,1) || staging (tid>=64) ----
    if (tid < 2) {
        compute_align(b, tid, skpt, rkpt, lkpt, rpose, lpose,
                      perm, ralign, lalign, affsh + tid * 12);
    } else if (tid == 2) {
        *((uint2*)(msh16 + NVERT * 4)) = make_uint2(0u, 0u);  // dummy slot
    } else if (tid >= 64) {
        const int t = tid - 64;
        const float* g = svert + (size_t)b * NV3;
        unsigned lead = (4u - ((unsigned)(((size_t)g) >> 2) & 3u)) & 3u;
        unsigned nb4 = ((unsigned)NV3 - lead) >> 2;
        if (t == 0) for (unsigned e = 0; e < lead; ++e) pack_one(msh16, e, g[e]);
        if (t == 1) for (unsigned e = lead + 4u * nb4; e < (unsigned)NV3; ++e) pack_one(msh16, e, g[e]);
        const f32x4* g4 = (const f32x4*)(g + lead);
        for (unsigned i4 = (unsigned)t; i4 < nb4; i4 += 960u) {
            f32x4 q = g4[i4];
            unsigned p = lead + 4u * i4;
            pack_one(msh16, p,     q.x);
            pack_one(msh16, p + 1, q.y);
            pack_one(msh16, p + 2, q.z);
            pack_one(msh16, p + 3, q.w);
        }
        stage_load(rv + (size_t)b * MV3, hstage,       MV3, t, 960);
        stage_load(lv + (size_t)b * MV3, hstage + MV3, MV3, t, 960);
    }

    // coalesced prepacked record reads (all threads, 8 records each)
    unsigned w0[8], w1[8], w2[8], w3[8], w4[8];
    #pragma unroll
    for (int k = 0; k < 8; ++k) {
        int j = k * 1024 + tid;
        w0[k] = tab[j];
        w1[k] = tab[NBDRY + j];
        w2[k] = tab[2 * NBDRY + j];
        w3[k] = tab[3 * NBDRY + j];
        w4[k] = tab[4 * NBDRY + j];
    }
    __syncthreads();   // mesh+hands staged, affines ready

    // ---- phase B: transform + scatter hand verts ----
    for (int i = tid; i < 2 * MVERT; i += 1024) {
        int h = (i >= MVERT) ? 1 : 0;
        int nn = i - h * MVERT;
        const int* hidx = h ? lidx : ridx;
        const float* M = affsh + h * 12;
        const float* p = hstage + h * MV3 + nn * 3;
        float p0 = p[0], p1 = p[1], p2 = p[2];
        float o0 = p0 * M[0] + p1 * M[3] + p2 * M[6] + M[9];
        float o1 = p0 * M[1] + p1 * M[4] + p2 * M[7] + M[10];
        float o2 = p0 * M[2] + p1 * M[5] + p2 * M[8] + M[11];
        ((uint2*)msh16)[hidx[nn]] = make_uint2(f2bf(o0) | (f2bf(o1) << 16), f2bf(o2));
    }
    __syncthreads();

    const uint2* mesh = (const uint2*)msh16;

    // self values -> registers (post-scatter), kept across iterations
    uint2 up[8];
    #pragma unroll
    for (int k = 0; k < 8; ++k) up[k] = mesh[(w4[k] >> 14) & 0x3FFFu];

    // ---- phase C: 5 Jacobi smoothing iterations (branchless gathers) ----
#define NB_GATHER(idx) { uint2 m = mesh[(idx)]; \
        sx += bfu(m.x << 16); sy += bfu(m.x & 0xFFFF0000u); sz += bfu(m.y << 16); }
    for (int itr = 0; itr < ITERS; ++itr) {
        #pragma unroll
        for (int k = 0; k < 8; ++k) {
            float sx = 0.f, sy = 0.f, sz = 0.f;
            NB_GATHER(w0[k] & 0x3FFFu);
            NB_GATHER((w0[k] >> 14) & 0x3FFFu);
            NB_GATHER(w1[k] & 0x3FFFu);
            NB_GATHER((w1[k] >> 14) & 0x3FFFu);
            NB_GATHER(w2[k] & 0x3FFFu);
            NB_GATHER((w2[k] >> 14) & 0x3FFFu);
            NB_GATHER(w3[k] & 0x3FFFu);
            NB_GATHER((w3[k] >> 14) & 0x3FFFu);
            NB_GATHER(w4[k] & 0x3FFFu);
            float hinv = 0.5f * __builtin_amdgcn_rcpf((float)(w4[k] >> 28));
            float ux = 0.5f * bfu(up[k].x << 16)         + hinv * sx;
            float uy = 0.5f * bfu(up[k].x & 0xFFFF0000u) + hinv * sy;
            float uz = 0.5f * bfu(up[k].y << 16)         + hinv * sz;
            up[k] = make_uint2(f2bf(ux) | (f2bf(uy) << 16), f2bf(uz));
        }
        __syncthreads();
        #pragma unroll
        for (int k = 0; k < 8; ++k) {
            ((uint2*)msh16)[(w4[k] >> 14) & 0x3FFFu] = up[k];
        }
        __syncthreads();
    }
#undef NB_GATHER

    // ---- phase D: write back, dense aligned f32x4 ----
    float* dst = out + (size_t)b * NV3;
    const unsigned lead = (4u - ((unsigned)(((size_t)dst) >> 2) & 3u)) & 3u;
#define COMP(i, val) { unsigned v_ = (i) / 3u; unsigned c_ = (i) - v_ * 3u; \
        uint2 m_ = mesh[v_]; \
        val = (c_ == 0u) ? bfu(m_.x << 16) : (c_ == 1u) ? bfu(m_.x & 0xFFFF0000u) : bfu(m_.y << 16); }
    if ((unsigned)tid < lead) {
        float v; COMP((unsigned)tid, v);
        dst[tid] = v;
    }
    const unsigned nb4 = ((unsigned)NV3 - lead) >> 2;
    f32x4* dst4 = (f32x4*)(dst + lead);
    for (unsigned i4 = (unsigned)tid; i4 < nb4; i4 += 1024u) {
        unsigned i0 = lead + 4u * i4;
        f32x4 o;
        COMP(i0 + 0u, o.x);
        COMP(i0 + 1u, o.y);
        COMP(i0 + 2u, o.z);
        COMP(i0 + 3u, o.w);
        dst4[i4] = o;
    }
    const unsigned done = lead + 4u * nb4;
    if ((unsigned)tid < (unsigned)NV3 - done) {
        float v; COMP(done + (unsigned)tid, v);
        dst[done + tid] = v;
    }
#undef COMP
}

extern "C" void kernel_launch(void* const* d_in, const int* in_sizes, int n_in,
                              void* d_out, int out_size, void* d_ws, size_t ws_size,
                              hipStream_t stream) {
    const float* svert  = (const float*)d_in[0];
    const float* skpt   = (const float*)d_in[1];
    const float* rv     = (const float*)d_in[2];
    const float* rk     = (const float*)d_in[3];
    const float* rpose  = (const float*)d_in[4];
    const float* lv     = (const float*)d_in[5];
    const float* lk     = (const float*)d_in[6];
    const float* lpose  = (const float*)d_in[7];
    const int*   perm   = (const int*)d_in[8];
    const int*   ralign = (const int*)d_in[9];
    const int*   lalign = (const int*)d_in[10];
    const int*   ridx   = (const int*)d_in[11];
    const int*   lidx   = (const int*)d_in[12];
    const int*   bidx   = (const int*)d_in[15];
    const int*   vnbr   = (const int*)d_in[16];
    float* out = (float*)d_out;

    unsigned* tab = (unsigned*)d_ws;   // 5*8192 u32 = 160 KB

    pack_kernel<<<64, 128, 0, stream>>>(bidx, vnbr, tab);
    fused_kernel<<<BB, 1024, 0, stream>>>(svert, skpt, rv, rk, rpose,
                                          lv, lk, lpose, perm, ralign, lalign,
                                          ridx, lidx, tab, out);
}

// Round 11
// 57.349 us; speedup vs baseline: 1.4815x; 1.0929x over previous
//
#include <hip/hip_runtime.h>

#define BB    256
#define NVERT 10475
#define NKPT  144
#define MVERT 778
#define MKPT  21
#define NBDRY 8192
#define KNB   9
#define ITERS 5
#define NV3   (NVERT * 3)
#define MV3   (MVERT * 3)   // 2334

typedef float f32x4 __attribute__((ext_vector_type(4)));

static __device__ __forceinline__ float bfu(unsigned hi16) {
    return __uint_as_float(hi16);
}
// f32 -> bf16 bits, round-to-nearest-even
static __device__ __forceinline__ unsigned f2bf(float f) {
    unsigned u = __float_as_uint(f);
    u += 0x7FFFu + ((u >> 16) & 1u);
    return u >> 16;
}
// pack one float (global dword position p within the batch slice) into the
// bf16 mesh: vertex = p/3, component = p%3, stored as ushort at v*4+c.
static __device__ __forceinline__ void pack_one(unsigned short* msh16, unsigned p, float val) {
    unsigned v = p / 3u;
    unsigned c = p - v * 3u;
    msh16[v * 4u + c] = (unsigned short)f2bf(val);
}

static __device__ __forceinline__ float frcp(float x)  { return __builtin_amdgcn_rcpf(x); }
static __device__ __forceinline__ float frsq(float x)  { return __builtin_amdgcn_rsqf(x); }
static __device__ __forceinline__ float fsqrt_(float x){ return __builtin_amdgcn_sqrtf(x); }

// dense f32x4 copy global -> LDS staging
static __device__ __forceinline__ void stage_load(const float* __restrict__ g,
                                                  float* sh, int n, int t, int nt) {
    unsigned lead = (4u - ((unsigned)(((size_t)g) >> 2) & 3u)) & 3u;
    unsigned nb4 = ((unsigned)n - lead) >> 2;
    if (t == 0) for (unsigned e = 0; e < lead; ++e) sh[e] = g[e];
    if (t == 1) for (unsigned e = lead + 4u * nb4; e < (unsigned)n; ++e) sh[e] = g[e];
    const f32x4* g4 = (const f32x4*)(g + lead);
    for (unsigned i4 = (unsigned)t; i4 < nb4; i4 += (unsigned)nt) {
        f32x4 q = g4[i4];
        unsigned p = lead + 4u * i4;
        sh[p] = q.x; sh[p + 1] = q.y; sh[p + 2] = q.z; sh[p + 3] = q.w;
    }
}

// one symmetric Jacobi rotation on pivot (p,q); A1*,A2* are the two
// off-pivot symmetric elements per side; V?? the 4 eigenvector-column pairs.
#define JROT(DP, DQ, EPQ, A1P, A1Q, A2P, A2Q, VP0, VQ0, VP1, VQ1, VP2, VQ2, VP3, VQ3) { \
    float apq = EPQ; \
    float th = (DQ - DP) * 0.5f * frcp(apq); \
    float t = copysignf(frcp(fabsf(th) + fsqrt_(th*th + 1.0f)), th); \
    t = (fabsf(apq) > 1e-30f) ? t : 0.0f; \
    float cj = frsq(t*t + 1.0f); \
    float sj = t * cj; \
    DP -= t * apq; DQ += t * apq; EPQ = 0.0f; \
    { float x_ = A1P, y_ = A1Q; A1P = cj*x_ - sj*y_; A1Q = sj*x_ + cj*y_; } \
    { float x_ = A2P, y_ = A2Q; A2P = cj*x_ - sj*y_; A2Q = sj*x_ + cj*y_; } \
    { float x_ = VP0, y_ = VQ0; VP0 = cj*x_ - sj*y_; VQ0 = sj*x_ + cj*y_; } \
    { float x_ = VP1, y_ = VQ1; VP1 = cj*x_ - sj*y_; VQ1 = sj*x_ + cj*y_; } \
    { float x_ = VP2, y_ = VQ2; VP2 = cj*x_ - sj*y_; VQ2 = sj*x_ + cj*y_; } \
    { float x_ = VP3, y_ = VQ3; VP3 = cj*x_ - sj*y_; VQ3 = sj*x_ + cj*y_; } \
}

#define JSWEEP \
    JROT(D0,D1,E01, E02,E12, E03,E13, V00,V01,V10,V11,V20,V21,V30,V31) \
    JROT(D0,D2,E02, E01,E12, E03,E23, V00,V02,V10,V12,V20,V22,V30,V32) \
    JROT(D0,D3,E03, E01,E13, E02,E23, V00,V03,V10,V13,V20,V23,V30,V33) \
    JROT(D1,D2,E12, E01,E02, E13,E23, V01,V02,V11,V12,V21,V22,V31,V32) \
    JROT(D1,D3,E13, E01,E03, E12,E23, V01,V03,V11,V13,V21,V23,V31,V33) \
    JROT(D2,D3,E23, E02,E03, E12,E13, V02,V03,V12,V13,V22,V23,V32,V33)

// ---------------------------------------------------------------------------
// Per (batch, hand) rigid alignment. Fully-unrolled branchless f32 Jacobi
// (6 sweeps), native rcp/rsq/sqrt/sin/cos: short serial chain (~2-3us) so it
// hides under the staging phase when run on lanes 0,1 of wave 0.
// ---------------------------------------------------------------------------
static __device__ void compute_align(
    int b, int h,
    const float* __restrict__ skpt, const float* __restrict__ rkpt,
    const float* __restrict__ lkpt, const float* __restrict__ rpose,
    const float* __restrict__ lpose, const int* __restrict__ perm,
    const int* __restrict__ ralign, const int* __restrict__ lalign,
    float* o)
{
    const float* pose = (h ? lpose : rpose) + b * 3;
    const float* kpt  = (h ? lkpt : rkpt) + (size_t)b * MKPT * 3;
    const int* alidx  = h ? lalign : ralign;

    float ax = pose[0], ay = pose[1], az = pose[2];
    float ang = fsqrt_(ax*ax + ay*ay + az*az);
    float ia = frcp(ang + 1e-8f);
    float x = ax*ia, y = ay*ia, z = az*ia;
    float c = __cosf(ang), s = __sinf(ang), Cc = 1.0f - c;
    float A00 = c + x*x*Cc,   A01 = x*y*Cc - z*s, A02 = x*z*Cc + y*s;
    float A10 = y*x*Cc + z*s, A11 = c + y*y*Cc,   A12 = y*z*Cc - x*s;
    float A20 = z*x*Cc - y*s, A21 = z*y*Cc + x*s, A22 = c + z*z*Cc;

    float sX0=0,sX1=0,sX2=0, sY0=0,sY1=0,sY2=0;
    float S00=0,S01=0,S02=0,S10=0,S11=0,S12=0,S20=0,S21=0,S22=0;
    #pragma unroll
    for (int n = 0; n < MKPT; ++n) {
        int pi = perm[n];
        float p0 = kpt[pi*3+0], p1 = kpt[pi*3+1], p2 = kpt[pi*3+2];
        float X0 = A00*p0 + A10*p1 + A20*p2;
        float X1 = A01*p0 + A11*p1 + A21*p2;
        float X2 = A02*p0 + A12*p1 + A22*p2;
        int qi = alidx[n];
        const float* yp = skpt + ((size_t)b * NKPT + qi) * 3;
        float Y0 = yp[0], Y1 = yp[1], Y2 = yp[2];
        sX0 += X0; sX1 += X1; sX2 += X2;
        sY0 += Y0; sY1 += Y1; sY2 += Y2;
        S00 += X0*Y0; S01 += X0*Y1; S02 += X0*Y2;
        S10 += X1*Y0; S11 += X1*Y1; S12 += X1*Y2;
        S20 += X2*Y0; S21 += X2*Y1; S22 += X2*Y2;
    }
    const float invN = 1.0f / (float)MKPT;
    float C00 = S00 - sX0*sY0*invN, C01 = S01 - sX0*sY1*invN, C02 = S02 - sX0*sY2*invN;
    float C10 = S10 - sX1*sY0*invN, C11 = S11 - sX1*sY1*invN, C12 = S12 - sX1*sY2*invN;
    float C20 = S20 - sX2*sY0*invN, C21 = S21 - sX2*sY1*invN, C22 = S22 - sX2*sY2*invN;

    // Horn's 4x4 N, symmetric scalars
    float D0 = C00 + C11 + C22;
    float E01 = C21 - C12, E02 = C02 - C20, E03 = C10 - C01;
    float D1 = C00 - C11 - C22, E12 = C01 + C10, E13 = C02 + C20;
    float D2 = -C00 + C11 - C22, E23 = C12 + C21;
    float D3 = -C00 - C11 + C22;

    float V00=1,V01=0,V02=0,V03=0;
    float V10=0,V11=1,V12=0,V13=0;
    float V20=0,V21=0,V22=1,V23=0;
    float V30=0,V31=0,V32=0,V33=1;

    JSWEEP JSWEEP JSWEEP JSWEEP JSWEEP JSWEEP   // 6 sweeps, fully unrolled

    float dm = D0, w = V00, qx = V10, qy = V20, qz = V30;
    bool c1 = D1 > dm; dm = c1?D1:dm; w = c1?V01:w; qx = c1?V11:qx; qy = c1?V21:qy; qz = c1?V31:qz;
    bool c2 = D2 > dm; dm = c2?D2:dm; w = c2?V02:w; qx = c2?V12:qx; qy = c2?V22:qy; qz = c2?V32:qz;
    bool c3 = D3 > dm;                w = c3?V03:w; qx = c3?V13:qx; qy = c3?V23:qy; qz = c3?V33:qz;

    float R00 = 1.0f - 2.0f*(qy*qy + qz*qz), R01 = 2.0f*(qx*qy - w*qz), R02 = 2.0f*(qx*qz + w*qy);
    float R10 = 2.0f*(qx*qy + w*qz), R11 = 1.0f - 2.0f*(qx*qx + qz*qz), R12 = 2.0f*(qy*qz - w*qx);
    float R20 = 2.0f*(qx*qz - w*qy), R21 = 2.0f*(qy*qz + w*qx), R22 = 1.0f - 2.0f*(qx*qx + qy*qy);

    float mX0 = sX0*invN, mX1 = sX1*invN, mX2 = sX2*invN;
    float mY0 = sY0*invN, mY1 = sY1*invN, mY2 = sY2*invN;

    o[0]  = A00*R00 + A01*R10 + A02*R20;
    o[1]  = A00*R01 + A01*R11 + A02*R21;
    o[2]  = A00*R02 + A01*R12 + A02*R22;
    o[3]  = A10*R00 + A11*R10 + A12*R20;
    o[4]  = A10*R01 + A11*R11 + A12*R21;
    o[5]  = A10*R02 + A11*R12 + A12*R22;
    o[6]  = A20*R00 + A21*R10 + A22*R20;
    o[7]  = A20*R01 + A21*R11 + A22*R21;
    o[8]  = A20*R02 + A21*R12 + A22*R22;
    o[9]  = mY0 - (mX0*R00 + mX1*R10 + mX2*R20);
    o[10] = mY1 - (mX0*R01 + mX1*R11 + mX2*R21);
    o[11] = mY2 - (mX0*R02 + mX1*R12 + mX2*R22);
}

// ---------------------------------------------------------------------------
// Pack-only kernel (64 blocks x 128 thr): the address-divergent vnbr-row
// gathers paid once, spread over 64 CUs.
//   w0..w3 = n0..n7 pairs (14b, invalid -> NVERT dummy)
//   w4     = n8 | bi<<14 | cnt<<28
// ---------------------------------------------------------------------------
__global__ __launch_bounds__(128) void pack_kernel(
    const int* __restrict__ bidx, const int* __restrict__ vnbr,
    unsigned* __restrict__ tab)
{
    int j = blockIdx.x * 128 + threadIdx.x; // 0..8191
    int bi = bidx[j];
    const int* row = vnbr + (size_t)bi * KNB;
    unsigned n[9]; unsigned cnt = 0;
    #pragma unroll
    for (int e = 0; e < 9; ++e) {
        int vv = row[e];
        if (vv >= 0) { n[e] = (unsigned)vv; ++cnt; }
        else         { n[e] = (unsigned)NVERT; }
    }
    if (cnt == 0) cnt = 1;
    tab[0 * NBDRY + j] = n[0] | (n[1] << 14);
    tab[1 * NBDRY + j] = n[2] | (n[3] << 14);
    tab[2 * NBDRY + j] = n[4] | (n[5] << 14);
    tab[3 * NBDRY + j] = n[6] | (n[7] << 14);
    tab[4 * NBDRY + j] = n[8] | ((unsigned)bi << 14) | (cnt << 28);
}

// ---------------------------------------------------------------------------
// Main fused kernel: one WG (1024) / batch. Per-thread loop state ~56 VGPRs
// (w0..w4[8]=40 + up[8]=16): spill-free. Branchless 9-gather loop.
// ---------------------------------------------------------------------------
__global__ __launch_bounds__(1024, 1) void fused_kernel(
    const float* __restrict__ svert,  // [B, NVERT, 3]
    const float* __restrict__ skpt,   // [B, NKPT, 3]
    const float* __restrict__ rv,     // [B, MVERT, 3]
    const float* __restrict__ rkpt,   // [B, MKPT, 3]
    const float* __restrict__ rpose,  // [B, 3]
    const float* __restrict__ lv,
    const float* __restrict__ lkpt,
    const float* __restrict__ lpose,
    const int*   __restrict__ perm,
    const int*   __restrict__ ralign,
    const int*   __restrict__ lalign,
    const int*   __restrict__ ridx,   // [MVERT]
    const int*   __restrict__ lidx,
    const unsigned* __restrict__ tab, // [5, NBDRY]
    float*       __restrict__ out)    // [B, NVERT, 3]
{
    __shared__ __align__(16) unsigned short msh16[(NVERT + 1) * 4];  // 83.8 KB
    __shared__ __align__(16) float hstage[2 * MV3];                  // 18.7 KB
    __shared__ float affsh[24];
    const int b = blockIdx.x;
    const int tid = threadIdx.x;

    // ---- phase A: align (lanes 0,1 of wave 0) || staging (tid>=64) ----
    if (tid < 2) {
        compute_align(b, tid, skpt, rkpt, lkpt, rpose, lpose,
                      perm, ralign, lalign, affsh + tid * 12);
    } else if (tid == 2) {
        *((uint2*)(msh16 + NVERT * 4)) = make_uint2(0u, 0u);  // dummy slot
    } else if (tid >= 64) {
        const int t = tid - 64;
        const float* g = svert + (size_t)b * NV3;
        unsigned lead = (4u - ((unsigned)(((size_t)g) >> 2) & 3u)) & 3u;
        unsigned nb4 = ((unsigned)NV3 - lead) >> 2;
        if (t == 0) for (unsigned e = 0; e < lead; ++e) pack_one(msh16, e, g[e]);
        if (t == 1) for (unsigned e = lead + 4u * nb4; e < (unsigned)NV3; ++e) pack_one(msh16, e, g[e]);
        const f32x4* g4 = (const f32x4*)(g + lead);
        for (unsigned i4 = (unsigned)t; i4 < nb4; i4 += 960u) {
            f32x4 q = g4[i4];
            unsigned p = lead + 4u * i4;
            pack_one(msh16, p,     q.x);
            pack_one(msh16, p + 1, q.y);
            pack_one(msh16, p + 2, q.z);
            pack_one(msh16, p + 3, q.w);
        }
        stage_load(rv + (size_t)b * MV3, hstage,       MV3, t, 960);
        stage_load(lv + (size_t)b * MV3, hstage + MV3, MV3, t, 960);
    }

    // coalesced prepacked record reads (all threads, 8 records each)
    unsigned w0[8], w1[8], w2[8], w3[8], w4[8];
    #pragma unroll
    for (int k = 0; k < 8; ++k) {
        int j = k * 1024 + tid;
        w0[k] = tab[j];
        w1[k] = tab[NBDRY + j];
        w2[k] = tab[2 * NBDRY + j];
        w3[k] = tab[3 * NBDRY + j];
        w4[k] = tab[4 * NBDRY + j];
    }
    __syncthreads();   // mesh+hands staged, affines ready

    // ---- phase B: transform + scatter hand verts ----
    for (int i = tid; i < 2 * MVERT; i += 1024) {
        int h = (i >= MVERT) ? 1 : 0;
        int nn = i - h * MVERT;
        const int* hidx = h ? lidx : ridx;
        const float* M = affsh + h * 12;
        const float* p = hstage + h * MV3 + nn * 3;
        float p0 = p[0], p1 = p[1], p2 = p[2];
        float o0 = p0 * M[0] + p1 * M[3] + p2 * M[6] + M[9];
        float o1 = p0 * M[1] + p1 * M[4] + p2 * M[7] + M[10];
        float o2 = p0 * M[2] + p1 * M[5] + p2 * M[8] + M[11];
        ((uint2*)msh16)[hidx[nn]] = make_uint2(f2bf(o0) | (f2bf(o1) << 16), f2bf(o2));
    }
    __syncthreads();

    const uint2* mesh = (const uint2*)msh16;

    // self values -> registers (post-scatter), kept across iterations
    uint2 up[8];
    #pragma unroll
    for (int k = 0; k < 8; ++k) up[k] = mesh[(w4[k] >> 14) & 0x3FFFu];

    // ---- phase C: 5 Jacobi smoothing iterations (branchless gathers) ----
#define NB_GATHER(idx) { uint2 m = mesh[(idx)]; \
        sx += bfu(m.x << 16); sy += bfu(m.x & 0xFFFF0000u); sz += bfu(m.y << 16); }
    for (int itr = 0; itr < ITERS; ++itr) {
        #pragma unroll
        for (int k = 0; k < 8; ++k) {
            float sx = 0.f, sy = 0.f, sz = 0.f;
            NB_GATHER(w0[k] & 0x3FFFu);
            NB_GATHER((w0[k] >> 14) & 0x3FFFu);
            NB_GATHER(w1[k] & 0x3FFFu);
            NB_GATHER((w1[k] >> 14) & 0x3FFFu);
            NB_GATHER(w2[k] & 0x3FFFu);
            NB_GATHER((w2[k] >> 14) & 0x3FFFu);
            NB_GATHER(w3[k] & 0x3FFFu);
            NB_GATHER((w3[k] >> 14) & 0x3FFFu);
            NB_GATHER(w4[k] & 0x3FFFu);
            float hinv = 0.5f * frcp((float)(w4[k] >> 28));
            float ux = 0.5f * bfu(up[k].x << 16)         + hinv * sx;
            float uy = 0.5f * bfu(up[k].x & 0xFFFF0000u) + hinv * sy;
            float uz = 0.5f * bfu(up[k].y << 16)         + hinv * sz;
            up[k] = make_uint2(f2bf(ux) | (f2bf(uy) << 16), f2bf(uz));
        }
        __syncthreads();
        #pragma unroll
        for (int k = 0; k < 8; ++k) {
            ((uint2*)msh16)[(w4[k] >> 14) & 0x3FFFu] = up[k];
        }
        __syncthreads();
    }
#undef NB_GATHER

    // ---- phase D: write back, dense aligned f32x4 ----
    float* dst = out + (size_t)b * NV3;
    const unsigned lead = (4u - ((unsigned)(((size_t)dst) >> 2) & 3u)) & 3u;
#define COMP(i, val) { unsigned v_ = (i) / 3u; unsigned c_ = (i) - v_ * 3u; \
        uint2 m_ = mesh[v_]; \
        val = (c_ == 0u) ? bfu(m_.x << 16) : (c_ == 1u) ? bfu(m_.x & 0xFFFF0000u) : bfu(m_.y << 16); }
    if ((unsigned)tid < lead) {
        float v; COMP((unsigned)tid, v);
        dst[tid] = v;
    }
    const unsigned nb4 = ((unsigned)NV3 - lead) >> 2;
    f32x4* dst4 = (f32x4*)(dst + lead);
    for (unsigned i4 = (unsigned)tid; i4 < nb4; i4 += 1024u) {
        unsigned i0 = lead + 4u * i4;
        f32x4 o;
        COMP(i0 + 0u, o.x);
        COMP(i0 + 1u, o.y);
        COMP(i0 + 2u, o.z);
        COMP(i0 + 3u, o.w);
        dst4[i4] = o;
    }
    const unsigned done = lead + 4u * nb4;
    if ((unsigned)tid < (unsigned)NV3 - done) {
        float v; COMP(done + (unsigned)tid, v);
        dst[done + tid] = v;
    }
#undef COMP
}

extern "C" void kernel_launch(void* const* d_in, const int* in_sizes, int n_in,
                              void* d_out, int out_size, void* d_ws, size_t ws_size,
                              hipStream_t stream) {
    const float* svert  = (const float*)d_in[0];
    const float* skpt   = (const float*)d_in[1];
    const float* rv     = (const float*)d_in[2];
    const float* rk     = (const float*)d_in[3];
    const float* rpose  = (const float*)d_in[4];
    const float* lv     = (const float*)d_in[5];
    const float* lk     = (const float*)d_in[6];
    const float* lpose  = (const float*)d_in[7];
    const int*   perm   = (const int*)d_in[8];
    const int*   ralign = (const int*)d_in[9];
    const int*   lalign = (const int*)d_in[10];
    const int*   ridx   = (const int*)d_in[11];
    const int*   lidx   = (const int*)d_in[12];
    const int*   bidx   = (const int*)d_in[15];
    const int*   vnbr   = (const int*)d_in[16];
    float* out = (float*)d_out;

    unsigned* tab = (unsigned*)d_ws;   // 5*8192 u32 = 160 KB

    pack_kernel<<<64, 128, 0, stream>>>(bidx, vnbr, tab);
    fused_kernel<<<BB, 1024, 0, stream>>>(svert, skpt, rv, rk, rpose,
                                          lv, lk, lpose, perm, ralign, lalign,
                                          ridx, lidx, tab, out);
}

// Round 12
// 55.578 us; speedup vs baseline: 1.5287x; 1.0319x over previous
//
#include <hip/hip_runtime.h>

#define BB    256
#define NVERT 10475
#define NKPT  144
#define MVERT 778
#define MKPT  21
#define NBDRY 8192
#define KNB   9
#define ITERS 5
#define NV3   (NVERT * 3)
#define MV3   (MVERT * 3)   // 2334

typedef float f32x4 __attribute__((ext_vector_type(4)));

static __device__ __forceinline__ float bfu(unsigned hi16) {
    return __uint_as_float(hi16);
}
// f32 -> bf16 bits, round-to-nearest-even
static __device__ __forceinline__ unsigned f2bf(float f) {
    unsigned u = __float_as_uint(f);
    u += 0x7FFFu + ((u >> 16) & 1u);
    return u >> 16;
}
// pack one float (global dword position p within the batch slice) into the
// bf16 mesh: vertex = p/3, component = p%3, stored as ushort at v*4+c.
static __device__ __forceinline__ void pack_one(unsigned short* msh16, unsigned p, float val) {
    unsigned v = p / 3u;
    unsigned c = p - v * 3u;
    msh16[v * 4u + c] = (unsigned short)f2bf(val);
}

static __device__ __forceinline__ float frcp(float x)  { return __builtin_amdgcn_rcpf(x); }
static __device__ __forceinline__ float frsq(float x)  { return __builtin_amdgcn_rsqf(x); }
static __device__ __forceinline__ float fsqrt_(float x){ return __builtin_amdgcn_sqrtf(x); }

// dense f32x4 copy global -> LDS staging
static __device__ __forceinline__ void stage_load(const float* __restrict__ g,
                                                  float* sh, int n, int t, int nt) {
    unsigned lead = (4u - ((unsigned)(((size_t)g) >> 2) & 3u)) & 3u;
    unsigned nb4 = ((unsigned)n - lead) >> 2;
    if (t == 0) for (unsigned e = 0; e < lead; ++e) sh[e] = g[e];
    if (t == 1) for (unsigned e = lead + 4u * nb4; e < (unsigned)n; ++e) sh[e] = g[e];
    const f32x4* g4 = (const f32x4*)(g + lead);
    for (unsigned i4 = (unsigned)t; i4 < nb4; i4 += (unsigned)nt) {
        f32x4 q = g4[i4];
        unsigned p = lead + 4u * i4;
        sh[p] = q.x; sh[p + 1] = q.y; sh[p + 2] = q.z; sh[p + 3] = q.w;
    }
}

// one symmetric Jacobi rotation on pivot (p,q)
#define JROT(DP, DQ, EPQ, A1P, A1Q, A2P, A2Q, VP0, VQ0, VP1, VQ1, VP2, VQ2, VP3, VQ3) { \
    float apq = EPQ; \
    float th = (DQ - DP) * 0.5f * frcp(apq); \
    float t = copysignf(frcp(fabsf(th) + fsqrt_(th*th + 1.0f)), th); \
    t = (fabsf(apq) > 1e-30f) ? t : 0.0f; \
    float cj = frsq(t*t + 1.0f); \
    float sj = t * cj; \
    DP -= t * apq; DQ += t * apq; EPQ = 0.0f; \
    { float x_ = A1P, y_ = A1Q; A1P = cj*x_ - sj*y_; A1Q = sj*x_ + cj*y_; } \
    { float x_ = A2P, y_ = A2Q; A2P = cj*x_ - sj*y_; A2Q = sj*x_ + cj*y_; } \
    { float x_ = VP0, y_ = VQ0; VP0 = cj*x_ - sj*y_; VQ0 = sj*x_ + cj*y_; } \
    { float x_ = VP1, y_ = VQ1; VP1 = cj*x_ - sj*y_; VQ1 = sj*x_ + cj*y_; } \
    { float x_ = VP2, y_ = VQ2; VP2 = cj*x_ - sj*y_; VQ2 = sj*x_ + cj*y_; } \
    { float x_ = VP3, y_ = VQ3; VP3 = cj*x_ - sj*y_; VQ3 = sj*x_ + cj*y_; } \
}

#define JSWEEP \
    JROT(D0,D1,E01, E02,E12, E03,E13, V00,V01,V10,V11,V20,V21,V30,V31) \
    JROT(D0,D2,E02, E01,E12, E03,E23, V00,V02,V10,V12,V20,V22,V30,V32) \
    JROT(D0,D3,E03, E01,E13, E02,E23, V00,V03,V10,V13,V20,V23,V30,V33) \
    JROT(D1,D2,E12, E01,E02, E13,E23, V01,V02,V11,V12,V21,V22,V31,V32) \
    JROT(D1,D3,E13, E01,E03, E12,E23, V01,V03,V11,V13,V21,V23,V31,V33) \
    JROT(D2,D3,E23, E02,E03, E12,E13, V02,V03,V12,V13,V22,V23,V32,V33)

// ---------------------------------------------------------------------------
// Per (batch, hand) rigid alignment. Fully-unrolled branchless f32 Jacobi
// (6 sweeps), native rcp/rsq/sqrt/sin/cos.
// ---------------------------------------------------------------------------
static __device__ void compute_align(
    int b, int h,
    const float* __restrict__ skpt, const float* __restrict__ rkpt,
    const float* __restrict__ lkpt, const float* __restrict__ rpose,
    const float* __restrict__ lpose, const int* __restrict__ perm,
    const int* __restrict__ ralign, const int* __restrict__ lalign,
    float* o)
{
    const float* pose = (h ? lpose : rpose) + b * 3;
    const float* kpt  = (h ? lkpt : rkpt) + (size_t)b * MKPT * 3;
    const int* alidx  = h ? lalign : ralign;

    float ax = pose[0], ay = pose[1], az = pose[2];
    float ang = fsqrt_(ax*ax + ay*ay + az*az);
    float ia = frcp(ang + 1e-8f);
    float x = ax*ia, y = ay*ia, z = az*ia;
    float c = __cosf(ang), s = __sinf(ang), Cc = 1.0f - c;
    float A00 = c + x*x*Cc,   A01 = x*y*Cc - z*s, A02 = x*z*Cc + y*s;
    float A10 = y*x*Cc + z*s, A11 = c + y*y*Cc,   A12 = y*z*Cc - x*s;
    float A20 = z*x*Cc - y*s, A21 = z*y*Cc + x*s, A22 = c + z*z*Cc;

    float sX0=0,sX1=0,sX2=0, sY0=0,sY1=0,sY2=0;
    float S00=0,S01=0,S02=0,S10=0,S11=0,S12=0,S20=0,S21=0,S22=0;
    #pragma unroll
    for (int n = 0; n < MKPT; ++n) {
        int pi = perm[n];
        float p0 = kpt[pi*3+0], p1 = kpt[pi*3+1], p2 = kpt[pi*3+2];
        float X0 = A00*p0 + A10*p1 + A20*p2;
        float X1 = A01*p0 + A11*p1 + A21*p2;
        float X2 = A02*p0 + A12*p1 + A22*p2;
        int qi = alidx[n];
        const float* yp = skpt + ((size_t)b * NKPT + qi) * 3;
        float Y0 = yp[0], Y1 = yp[1], Y2 = yp[2];
        sX0 += X0; sX1 += X1; sX2 += X2;
        sY0 += Y0; sY1 += Y1; sY2 += Y2;
        S00 += X0*Y0; S01 += X0*Y1; S02 += X0*Y2;
        S10 += X1*Y0; S11 += X1*Y1; S12 += X1*Y2;
        S20 += X2*Y0; S21 += X2*Y1; S22 += X2*Y2;
    }
    const float invN = 1.0f / (float)MKPT;
    float C00 = S00 - sX0*sY0*invN, C01 = S01 - sX0*sY1*invN, C02 = S02 - sX0*sY2*invN;
    float C10 = S10 - sX1*sY0*invN, C11 = S11 - sX1*sY1*invN, C12 = S12 - sX1*sY2*invN;
    float C20 = S20 - sX2*sY0*invN, C21 = S21 - sX2*sY1*invN, C22 = S22 - sX2*sY2*invN;

    // Horn's 4x4 N, symmetric scalars
    float D0 = C00 + C11 + C22;
    float E01 = C21 - C12, E02 = C02 - C20, E03 = C10 - C01;
    float D1 = C00 - C11 - C22, E12 = C01 + C10, E13 = C02 + C20;
    float D2 = -C00 + C11 - C22, E23 = C12 + C21;
    float D3 = -C00 - C11 + C22;

    float V00=1,V01=0,V02=0,V03=0;
    float V10=0,V11=1,V12=0,V13=0;
    float V20=0,V21=0,V22=1,V23=0;
    float V30=0,V31=0,V32=0,V33=1;

    JSWEEP JSWEEP JSWEEP JSWEEP JSWEEP JSWEEP   // 6 sweeps, fully unrolled

    float dm = D0, w = V00, qx = V10, qy = V20, qz = V30;
    bool c1 = D1 > dm; dm = c1?D1:dm; w = c1?V01:w; qx = c1?V11:qx; qy = c1?V21:qy; qz = c1?V31:qz;
    bool c2 = D2 > dm; dm = c2?D2:dm; w = c2?V02:w; qx = c2?V12:qx; qy = c2?V22:qy; qz = c2?V32:qz;
    bool c3 = D3 > dm;                w = c3?V03:w; qx = c3?V13:qx; qy = c3?V23:qy; qz = c3?V33:qz;

    float R00 = 1.0f - 2.0f*(qy*qy + qz*qz), R01 = 2.0f*(qx*qy - w*qz), R02 = 2.0f*(qx*qz + w*qy);
    float R10 = 2.0f*(qx*qy + w*qz), R11 = 1.0f - 2.0f*(qx*qx + qz*qz), R12 = 2.0f*(qy*qz - w*qx);
    float R20 = 2.0f*(qx*qz - w*qy), R21 = 2.0f*(qy*qz + w*qx), R22 = 1.0f - 2.0f*(qx*qx + qy*qy);

    float mX0 = sX0*invN, mX1 = sX1*invN, mX2 = sX2*invN;
    float mY0 = sY0*invN, mY1 = sY1*invN, mY2 = sY2*invN;

    o[0]  = A00*R00 + A01*R10 + A02*R20;
    o[1]  = A00*R01 + A01*R11 + A02*R21;
    o[2]  = A00*R02 + A01*R12 + A02*R22;
    o[3]  = A10*R00 + A11*R10 + A12*R20;
    o[4]  = A10*R01 + A11*R11 + A12*R21;
    o[5]  = A10*R02 + A11*R12 + A12*R22;
    o[6]  = A20*R00 + A21*R10 + A22*R20;
    o[7]  = A20*R01 + A21*R11 + A22*R21;
    o[8]  = A20*R02 + A21*R12 + A22*R22;
    o[9]  = mY0 - (mX0*R00 + mX1*R10 + mX2*R20);
    o[10] = mY1 - (mX0*R01 + mX1*R11 + mX2*R21);
    o[11] = mY2 - (mX0*R02 + mX1*R12 + mX2*R22);
}

// ---------------------------------------------------------------------------
// Wide setup kernel (68 blocks x 128 thr), all batch-independent/divergent
// work paid once across 68 CUs:
//  blocks 0-3 : 512 (batch, hand) affines (fast-math align, ~3us chain)
//  blocks 4-67: pack 128 records each -> tab[5][NBDRY]
//   w0..w3 = n0..n7 pairs (14b, invalid -> NVERT dummy)
//   w4     = n8 | bi<<14 | cnt<<28
// ---------------------------------------------------------------------------
__global__ __launch_bounds__(128) void setup_kernel(
    const float* __restrict__ skpt, const float* __restrict__ rkpt,
    const float* __restrict__ lkpt, const float* __restrict__ rpose,
    const float* __restrict__ lpose, const int* __restrict__ perm,
    const int* __restrict__ ralign, const int* __restrict__ lalign,
    const int* __restrict__ bidx, const int* __restrict__ vnbr,
    float* __restrict__ aff, unsigned* __restrict__ tab)
{
    const int g = blockIdx.x;
    if (g < 4) {
        int t = g * 128 + threadIdx.x;   // 0..511
        compute_align(t >> 1, t & 1, skpt, rkpt, lkpt, rpose, lpose,
                      perm, ralign, lalign, aff + t * 12);
        return;
    }
    int j = (g - 4) * 128 + threadIdx.x; // 0..8191
    int bi = bidx[j];
    const int* row = vnbr + (size_t)bi * KNB;
    unsigned n[9]; unsigned cnt = 0;
    #pragma unroll
    for (int e = 0; e < 9; ++e) {
        int vv = row[e];
        if (vv >= 0) { n[e] = (unsigned)vv; ++cnt; }
        else         { n[e] = (unsigned)NVERT; }
    }
    if (cnt == 0) cnt = 1;
    tab[0 * NBDRY + j] = n[0] | (n[1] << 14);
    tab[1 * NBDRY + j] = n[2] | (n[3] << 14);
    tab[2 * NBDRY + j] = n[4] | (n[5] << 14);
    tab[3 * NBDRY + j] = n[6] | (n[7] << 14);
    tab[4 * NBDRY + j] = n[8] | ((unsigned)bi << 14) | (cnt << 28);
}

// ---------------------------------------------------------------------------
// Main fused kernel (round-8 structure, align-free): one WG (1024) / batch.
// Per-thread loop state ~56 VGPRs (w0..w4[8]=40 + up[8]=16): spill-free.
// Branchless 9-gather loop (wave-level LDS instruction count is the cost).
// ---------------------------------------------------------------------------
__global__ __launch_bounds__(1024, 1) void fused_kernel(
    const float* __restrict__ svert,  // [B, NVERT, 3]
    const float* __restrict__ rv,     // [B, MVERT, 3]
    const float* __restrict__ lv,
    const int*   __restrict__ ridx,   // [MVERT]
    const int*   __restrict__ lidx,
    const float* __restrict__ aff,    // [B*2, 12]
    const unsigned* __restrict__ tab, // [5, NBDRY]
    float*       __restrict__ out)    // [B, NVERT, 3]
{
    __shared__ __align__(16) unsigned short msh16[(NVERT + 1) * 4];  // 83.8 KB
    __shared__ __align__(16) float hstage[2 * MV3];                  // 18.7 KB
    __shared__ float affsh[24];
    const int b = blockIdx.x;
    const int tid = threadIdx.x;

    // ---- phase A: staging (all 1024 threads) + affine/table reads ----
    if (tid == 0) *((uint2*)(msh16 + NVERT * 4)) = make_uint2(0u, 0u);
    if (tid < 24) affsh[tid] = aff[b * 24 + tid];
    {
        const float* g = svert + (size_t)b * NV3;
        unsigned lead = (4u - ((unsigned)(((size_t)g) >> 2) & 3u)) & 3u;
        unsigned nb4 = ((unsigned)NV3 - lead) >> 2;
        if (tid == 0) for (unsigned e = 0; e < lead; ++e) pack_one(msh16, e, g[e]);
        if (tid == 1) for (unsigned e = lead + 4u * nb4; e < (unsigned)NV3; ++e) pack_one(msh16, e, g[e]);
        const f32x4* g4 = (const f32x4*)(g + lead);
        for (unsigned i4 = (unsigned)tid; i4 < nb4; i4 += 1024u) {
            f32x4 q = g4[i4];
            unsigned p = lead + 4u * i4;
            pack_one(msh16, p,     q.x);
            pack_one(msh16, p + 1, q.y);
            pack_one(msh16, p + 2, q.z);
            pack_one(msh16, p + 3, q.w);
        }
        stage_load(rv + (size_t)b * MV3, hstage,       MV3, tid, 1024);
        stage_load(lv + (size_t)b * MV3, hstage + MV3, MV3, tid, 1024);
    }
    unsigned w0[8], w1[8], w2[8], w3[8], w4[8];
    #pragma unroll
    for (int k = 0; k < 8; ++k) {
        int j = k * 1024 + tid;
        w0[k] = tab[j];
        w1[k] = tab[NBDRY + j];
        w2[k] = tab[2 * NBDRY + j];
        w3[k] = tab[3 * NBDRY + j];
        w4[k] = tab[4 * NBDRY + j];
    }
    __syncthreads();   // mesh+hands staged, affines visible

    // ---- phase B: transform + scatter hand verts ----
    for (int i = tid; i < 2 * MVERT; i += 1024) {
        int h = (i >= MVERT) ? 1 : 0;
        int nn = i - h * MVERT;
        const int* hidx = h ? lidx : ridx;
        const float* M = affsh + h * 12;
        const float* p = hstage + h * MV3 + nn * 3;
        float p0 = p[0], p1 = p[1], p2 = p[2];
        float o0 = p0 * M[0] + p1 * M[3] + p2 * M[6] + M[9];
        float o1 = p0 * M[1] + p1 * M[4] + p2 * M[7] + M[10];
        float o2 = p0 * M[2] + p1 * M[5] + p2 * M[8] + M[11];
        ((uint2*)msh16)[hidx[nn]] = make_uint2(f2bf(o0) | (f2bf(o1) << 16), f2bf(o2));
    }
    __syncthreads();

    const uint2* mesh = (const uint2*)msh16;

    // self values -> registers (post-scatter), kept across iterations
    uint2 up[8];
    #pragma unroll
    for (int k = 0; k < 8; ++k) up[k] = mesh[(w4[k] >> 14) & 0x3FFFu];

    // ---- phase C: 5 Jacobi smoothing iterations (branchless gathers) ----
#define NB_GATHER(idx) { uint2 m = mesh[(idx)]; \
        sx += bfu(m.x << 16); sy += bfu(m.x & 0xFFFF0000u); sz += bfu(m.y << 16); }
    for (int itr = 0; itr < ITERS; ++itr) {
        #pragma unroll
        for (int k = 0; k < 8; ++k) {
            float sx = 0.f, sy = 0.f, sz = 0.f;
            NB_GATHER(w0[k] & 0x3FFFu);
            NB_GATHER((w0[k] >> 14) & 0x3FFFu);
            NB_GATHER(w1[k] & 0x3FFFu);
            NB_GATHER((w1[k] >> 14) & 0x3FFFu);
            NB_GATHER(w2[k] & 0x3FFFu);
            NB_GATHER((w2[k] >> 14) & 0x3FFFu);
            NB_GATHER(w3[k] & 0x3FFFu);
            NB_GATHER((w3[k] >> 14) & 0x3FFFu);
            NB_GATHER(w4[k] & 0x3FFFu);
            float hinv = 0.5f * frcp((float)(w4[k] >> 28));
            float ux = 0.5f * bfu(up[k].x << 16)         + hinv * sx;
            float uy = 0.5f * bfu(up[k].x & 0xFFFF0000u) + hinv * sy;
            float uz = 0.5f * bfu(up[k].y << 16)         + hinv * sz;
            up[k] = make_uint2(f2bf(ux) | (f2bf(uy) << 16), f2bf(uz));
        }
        __syncthreads();
        #pragma unroll
        for (int k = 0; k < 8; ++k) {
            ((uint2*)msh16)[(w4[k] >> 14) & 0x3FFFu] = up[k];
        }
        __syncthreads();
    }
#undef NB_GATHER

    // ---- phase D: write back, dense aligned f32x4 ----
    float* dst = out + (size_t)b * NV3;
    const unsigned lead = (4u - ((unsigned)(((size_t)dst) >> 2) & 3u)) & 3u;
#define COMP(i, val) { unsigned v_ = (i) / 3u; unsigned c_ = (i) - v_ * 3u; \
        uint2 m_ = mesh[v_]; \
        val = (c_ == 0u) ? bfu(m_.x << 16) : (c_ == 1u) ? bfu(m_.x & 0xFFFF0000u) : bfu(m_.y << 16); }
    if ((unsigned)tid < lead) {
        float v; COMP((unsigned)tid, v);
        dst[tid] = v;
    }
    const unsigned nb4 = ((unsigned)NV3 - lead) >> 2;
    f32x4* dst4 = (f32x4*)(dst + lead);
    for (unsigned i4 = (unsigned)tid; i4 < nb4; i4 += 1024u) {
        unsigned i0 = lead + 4u * i4;
        f32x4 o;
        COMP(i0 + 0u, o.x);
        COMP(i0 + 1u, o.y);
        COMP(i0 + 2u, o.z);
        COMP(i0 + 3u, o.w);
        dst4[i4] = o;
    }
    const unsigned done = lead + 4u * nb4;
    if ((unsigned)tid < (unsigned)NV3 - done) {
        float v; COMP(done + (unsigned)tid, v);
        dst[done + tid] = v;
    }
#undef COMP
}

extern "C" void kernel_launch(void* const* d_in, const int* in_sizes, int n_in,
                              void* d_out, int out_size, void* d_ws, size_t ws_size,
                              hipStream_t stream) {
    const float* svert  = (const float*)d_in[0];
    const float* skpt   = (const float*)d_in[1];
    const float* rv     = (const float*)d_in[2];
    const float* rk     = (const float*)d_in[3];
    const float* rpose  = (const float*)d_in[4];
    const float* lv     = (const float*)d_in[5];
    const float* lk     = (const float*)d_in[6];
    const float* lpose  = (const float*)d_in[7];
    const int*   perm   = (const int*)d_in[8];
    const int*   ralign = (const int*)d_in[9];
    const int*   lalign = (const int*)d_in[10];
    const int*   ridx   = (const int*)d_in[11];
    const int*   lidx   = (const int*)d_in[12];
    const int*   bidx   = (const int*)d_in[15];
    const int*   vnbr   = (const int*)d_in[16];
    float* out = (float*)d_out;

    float*    aff = (float*)d_ws;                       // 512*12 f32 = 24 KB
    unsigned* tab = (unsigned*)((char*)d_ws + 24576);   // 5*8192 u32 = 160 KB

    setup_kernel<<<68, 128, 0, stream>>>(skpt, rk, lk, rpose, lpose,
                                         perm, ralign, lalign, bidx, vnbr,
                                         aff, tab);
    fused_kernel<<<BB, 1024, 0, stream>>>(svert, rv, lv, ridx, lidx,
                                          aff, tab, out);
}